// Round 13
// baseline (558.999 us; speedup 1.0000x reference)
//
#include <hip/hip_runtime.h>
#include <hip/hip_bf16.h>
#include <math.h>

#define B_ 8
#define C_ 256
#define S_ 64
#define H_ 128
#define W_ 128
#define HW_ (H_*W_)
#define P_ (B_*HW_)

typedef __attribute__((ext_vector_type(8))) short short8;
typedef __attribute__((ext_vector_type(4))) float f32x4;

__device__ __forceinline__ unsigned short f2b(float f){
    __hip_bfloat16 h = __float2bfloat16(f);
    return *reinterpret_cast<unsigned short*>(&h);
}
__device__ __forceinline__ void up8(uint4 u, float* f){
    unsigned v0=u.x,v1=u.y,v2=u.z,v3=u.w;
    f[0]=__uint_as_float(v0<<16); f[1]=__uint_as_float(v0&0xffff0000u);
    f[2]=__uint_as_float(v1<<16); f[3]=__uint_as_float(v1&0xffff0000u);
    f[4]=__uint_as_float(v2<<16); f[5]=__uint_as_float(v2&0xffff0000u);
    f[6]=__uint_as_float(v3<<16); f[7]=__uint_as_float(v3&0xffff0000u);
}
__device__ __forceinline__ uint4 pk8(const float* f){
    uint4 u;
    u.x = (unsigned)f2b(f[0]) | ((unsigned)f2b(f[1])<<16);
    u.y = (unsigned)f2b(f[2]) | ((unsigned)f2b(f[3])<<16);
    u.z = (unsigned)f2b(f[4]) | ((unsigned)f2b(f[5])<<16);
    u.w = (unsigned)f2b(f[6]) | ((unsigned)f2b(f[7])<<16);
    return u;
}
__device__ __forceinline__ void gl2lds(const unsigned short* g, unsigned short* l){
    __builtin_amdgcn_global_load_lds((const __attribute__((address_space(1))) void*)g,
                                     (__attribute__((address_space(3))) void*)l, 16, 0, 0);
}

// All activations use C32-blocked layout: [b][C/32][HW][32] (bf16).

// ---------------- NCHW fp32 -> blocked bf16 pack (fused x+y via z) ----------------
__global__ __launch_bounds__(256) void pack_k(const float* __restrict__ inA,
                                              const float* __restrict__ inB,
                                              unsigned short* __restrict__ outA,
                                              unsigned short* __restrict__ outB)
{
    __shared__ unsigned short tl[64][72];
    const int t = threadIdx.x;
    const int p0 = blockIdx.x*64, c0 = blockIdx.y*64;
    const int sel = blockIdx.z >> 3, b = blockIdx.z & 7;
    const float* in = sel ? inB : inA;
    unsigned short* out = sel ? outB : outA;
    const float* ib = in + ((size_t)b*C_ + c0)*HW_ + p0;
    for (int i = t; i < 1024; i += 256){
        int ci = i >> 4, px = (i & 15)*4;
        float4 v = *(const float4*)(ib + (size_t)ci*HW_ + px);
        tl[px+0][ci]=f2b(v.x); tl[px+1][ci]=f2b(v.y); tl[px+2][ci]=f2b(v.z); tl[px+3][ci]=f2b(v.w);
    }
    __syncthreads();
    for (int i = t; i < 512; i += 256){
        int px = i >> 3, c8 = (i & 7)*8;
        int cc = c0 + c8;
        unsigned short* dst = out + ((size_t)b*8 + (cc>>5))*(size_t)HW_*32
                                  + (size_t)(p0+px)*32 + (cc&31);
        *(uint4*)dst = *(uint4*)&tl[px][c8];
    }
}

// ---------------- weight prepack: fragment-major [coT][kb][tap][lane][8] ----------------
__device__ __forceinline__ void packw(const float* __restrict__ src, unsigned short* __restrict__ dst,
                                      int e, int CO, int CI, int TAPS)
{
    int KB = CI/32;
    int ee = e & 7;
    int l  = (e>>3) & 63;
    int t2 = e >> 9;            // (coT*KB + kb)*TAPS + tap
    int tap = t2 % TAPS;
    int t3  = t2 / TAPS;        // coT*KB + kb
    int kb  = t3 % KB;
    int coT = t3 / KB;
    int co = coT*16 + (l & 15);
    int ci = kb*32 + (l >> 4)*8 + ee;
    float v = (TAPS==9) ? src[(size_t)(co*CI+ci)*9 + tap] : src[(size_t)co*CI + ci];
    dst[e] = f2b(v);
}

__global__ __launch_bounds__(256) void prep_k(const float* __restrict__ cq, const float* __restrict__ ckv,
                                              const float* __restrict__ q,  const float* __restrict__ kv,
                                              const float* __restrict__ f1, const float* __restrict__ f2,
                                              const float* __restrict__ dwk, const float* __restrict__ dwf,
                                              unsigned short* o_cq, unsigned short* o_ckv, unsigned short* o_q,
                                              unsigned short* o_kv, unsigned short* o_f1, unsigned short* o_f2,
                                              unsigned short* o_dwk, unsigned short* o_dwf)
{
    int i = blockIdx.x*256 + threadIdx.x;
    if      (i < 147456) packw(cq,  o_cq,  i,          64, 256, 9);
    else if (i < 294912) packw(ckv, o_ckv, i-147456,   64, 256, 9);
    else if (i < 331776) packw(q,   o_q,   i-294912,   64,  64, 9);
    else if (i < 339968) packw(kv,  o_kv,  i-331776,  128,  64, 1);
    else if (i < 471040) packw(f1,  o_f1,  i-339968,  256, 512, 1);
    else if (i < 536576) packw(f2,  o_f2,  i-471040,  256, 256, 1);
    else if (i < 537728) { int e=i-536576; o_dwk[e] = f2b(dwk[(e&127)*9 + (e>>7)]); }
    else if (i < 540032) { int e=i-537728; o_dwf[e] = f2b(dwf[(e&255)*9 + (e>>8)]); }
    else if (i < 540040) { o_dwf[i-537728] = 0; }   // 16B zero page for OOB halo
}

// ---------------- MFMA conv: BM=128; KS3: 4 waves all-M (MT2xNT4) @ 4 blk/CU; KS1: 2x2 @ 3 blk/CU ----------------
// KS3: each 1KB A ds_read feeds NT=4 MFMAs (256B LDS/MFMA, ceiling 60% MfmaUtil)
// AND 4 blocks/CU residency (84 VGPR x4 = 336/SIMD, 33.8KB x4 = 135KB LDS).
// A via global_load_lds dbuf (source-swizzled, hoisted bases); B direct from L2.
template<int C0,int C1,int COUT,int KS,int BN,int OUTM,int LNF>
__global__ __launch_bounds__(256, (KS==3)?4:3) void mconv_k(
    const unsigned short* __restrict__ in0, int s0,
    const unsigned short* __restrict__ in1, int s1,
    const unsigned short* __restrict__ wp, long wpbs,
    void* __restrict__ outp, int so,
    const unsigned short* __restrict__ in0B,
    const unsigned short* __restrict__ wpB2,
    void* __restrict__ outB,
    const unsigned short* __restrict__ zbuf,
    const float* __restrict__ lnw0, const float* __restrict__ lnb0,
    const float* __restrict__ lnw1, const float* __restrict__ lnb1,
    int ny, int nz)
{
    constexpr int CINT = C0+C1;
    constexpr int KB   = CINT/32;
    constexpr int KB0  = C0/32;
    constexpr int TAPS = KS*KS;
    constexpr int MT  = (KS==3)?2:4;
    constexpr int NT  = (KS==3)?4:(BN/32);
    constexpr int PXS = (KS==3)?66:128;
    constexpr int ASZ = (KS==3)? 4*66*32 : 8192;     // shorts per buffer
    constexpr int EP  = (OUTM==1) ? 64*132*2 : 128*BN;
    constexpr int SSZ = (2*ASZ > EP) ? 2*ASZ : EP;
    __shared__ alignas(16) unsigned short sbuf[SSZ];

    const int t = threadIdx.x;
    const int nper = (128*ny*nz) >> 3;
    int lin = (blockIdx.x & 7)*nper + (blockIdx.x >> 3);
    const int gy_ = lin % ny;
    int rem = lin / ny;
    const int gx_ = rem & 127;
    const int gz_ = rem >> 7;
    const int sel = gz_ >> 3;
    const int b   = gz_ & 7;
    const int cob = gy_*BN;

    const unsigned short* pin0 = sel ? in0B : in0;
    const unsigned short* wpb  = (sel ? wpB2 : wp) + (size_t)b*wpbs;

    int y0=0,x0=0; size_t p0=0;
    if (KS==3){ y0=(gx_>>1)*2; x0=(gx_&1)*64; }
    else p0 = (size_t)gx_*128;

    const int l = t&63, w = t>>6;
    const int wy = (KS==3)? w : (w>>1);
    const int wx = (KS==3)? 0 : (w&1);
    const int lrow = l&15, lk = l>>4;

    const size_t b0base = (size_t)b*HW_*s0;
    const size_t b1base = (size_t)b*HW_*s1;
    const size_t KSTEP = (size_t)HW_*32;             // per-kb source stride

    // ---- hoisted B bases: fragment (coT,kb,tap) at ((coT*KB+kb)*TAPS+tap)*512 ----
    const unsigned short* pB[NT];
    #pragma unroll
    for (int n=0;n<NT;++n)
        pB[n] = wpb + (size_t)((cob>>4) + wx*NT + n)*KB*TAPS*512 + l*8;
    auto loadB = [&](short8* dst, int kb, int tap){
        #pragma unroll
        for (int n=0;n<NT;++n)
            dst[n] = *(const short8*)(pB[n] + (size_t)(kb*TAPS+tap)*512);
    };

    f32x4 acc[MT][NT] = {};

    if (KS==3){
        // ---- hoisted A bases (C1==0 on all KS3 launches) ----
        const unsigned short* aptr[5]; bool aok[5];
        #pragma unroll
        for (int j=0;j<5;++j){
            int i = t + j*256;
            if (j<4 || i<1056){
                int slot=i&3, pr=i>>2;
                int px=pr%66, row=pr/66;
                int g = slot ^ (px&3) ^ ((px>>2)&3);
                int gy=y0+row-1, gx=x0+px-1;
                aok[j] = ((unsigned)gy<(unsigned)H_) & ((unsigned)gx<(unsigned)W_);
                size_t p=(size_t)gy*W_+gx;
                aptr[j] = pin0 + b0base + p*32 + g*8;
            }
        }
        auto issueA3 = [&](int kb, int bsel){
            unsigned short* dst = sbuf + bsel*ASZ;
            size_t kof = (size_t)kb*KSTEP;
            #pragma unroll
            for (int j=0;j<5;++j){
                int i = t + j*256;
                if (j<4 || i<1056){
                    const unsigned short* s = aok[j] ? aptr[j] + kof : zbuf;
                    gl2lds(s, dst + (size_t)i*8);
                }
            }
        };

        short8 bfs[3][NT];
        issueA3(0,0);
        loadB(bfs[0],0,0); loadB(bfs[1],0,1); loadB(bfs[2],0,2);
        for (int kb=0; kb<KB; ++kb){
            __syncthreads();
            if (kb+1<KB) issueA3(kb+1,(kb+1)&1);
            unsigned short* cur = sbuf + (kb&1)*ASZ;
            #pragma unroll
            for (int tap=0;tap<9;++tap){
                const int ky=tap/3, kx=tap%3;
                short8 af[MT];
                #pragma unroll
                for (int m=0;m<MT;++m){
                    int pl = w*32 + m*16 + lrow;
                    int r = (pl>>6)+ky, xx = (pl&63)+kx;
                    af[m] = *(const short8*)&cur[((r*PXS+xx)*4 + (lk^(xx&3)^((xx>>2)&3)))*8];
                }
                #pragma unroll
                for (int m=0;m<MT;++m)
                    #pragma unroll
                    for (int n=0;n<NT;++n)
                        acc[m][n] = __builtin_amdgcn_mfma_f32_16x16x32_bf16(af[m],bfs[tap%3][n],acc[m][n],0,0,0);
                if (tap+3 < 9)      loadB(bfs[tap%3], kb, tap+3);
                else if (kb+1<KB)   loadB(bfs[tap%3], kb+1, tap-6);
            }
        }
    } else {
        // ---- hoisted A bases (two inputs for concat) ----
        const unsigned short* a0[2]; const unsigned short* a1[2];
        #pragma unroll
        for (int j=0;j<2;++j){
            int i = t + j*256;
            int slot=i&3, px=i>>2;
            int g = slot ^ (px&3) ^ ((px>>2)&3);
            size_t p = p0+px;
            a0[j] = pin0 + b0base + p*32 + g*8;
            a1[j] = in1  + b1base + p*32 + g*8;
        }
        auto issueA1 = [&](int s, int bsel){
            unsigned short* dst = sbuf + bsel*ASZ;
            #pragma unroll
            for (int h=0;h<2;++h){
                const int kb = s*2+h;
                #pragma unroll
                for (int j=0;j<2;++j){
                    int i = t + j*256;
                    const unsigned short* sp;
                    if (C1==0 || kb < KB0) sp = a0[j] + (size_t)kb*KSTEP;
                    else                   sp = a1[j] + (size_t)(kb-KB0)*KSTEP;
                    gl2lds(sp, dst + (size_t)(h*4096 + i*8));
                }
            }
        };

        constexpr int KBS = (KB>=2) ? KB/2 : 1;
        short8 bfs[2][NT];
        issueA1(0,0);
        loadB(bfs[0],0,0); loadB(bfs[1],1,0);
        for (int s=0; s<KBS; ++s){
            __syncthreads();
            if (s+1<KBS) issueA1(s+1,(s+1)&1);
            unsigned short* cur = sbuf + (s&1)*ASZ;
            #pragma unroll
            for (int j=0;j<2;++j){
                short8 af[MT];
                #pragma unroll
                for (int m=0;m<MT;++m){
                    int pl = wy*64 + m*16 + lrow;
                    af[m] = *(const short8*)&cur[j*4096 + (pl*4 + (lk^(pl&3)^((pl>>2)&3)))*8];
                }
                #pragma unroll
                for (int m=0;m<MT;++m)
                    #pragma unroll
                    for (int n=0;n<NT;++n)
                        acc[m][n] = __builtin_amdgcn_mfma_f32_16x16x32_bf16(af[m],bfs[j][n],acc[m][n],0,0,0);
                if (s*2+j+2 < KB) loadB(bfs[j], s*2+j+2, 0);
            }
        }
    }
    __syncthreads();

    if (OUTM==1){
        // fp32 NCHW out via LDS transpose; BN=128: two co-half passes (wave wx==h owns half h)
        float* sf = (float*)sbuf;
        float* out = (float*)(sel ? outB : outp);
        #pragma unroll
        for (int h=0; h<BN/64; ++h){
            if (h) __syncthreads();
            if (BN==64 || wx==h){
                #pragma unroll
                for (int m=0;m<MT;++m)
                    #pragma unroll
                    for (int n=0;n<NT;++n){
                        int co_l = (BN==64 ? wx*32 : 0) + n*16 + lrow;
                        int pl0  = wy*64 + m*16 + lk*4;
                        *(f32x4*)&sf[co_l*132 + pl0] = acc[m][n];
                    }
            }
            __syncthreads();
            for (int i=t; i<2048; i+=256){
                int co = i>>5, pxg = i&31;
                f32x4 v = *(const f32x4*)&sf[co*132 + pxg*4];
                *(f32x4*)(out + ((size_t)(b*COUT + cob + h*64 + co))*HW_ + p0 + pxg*4) = v;
            }
        }
    } else if (LNF){
        // KS3 mapping: co = n*16+lrow, pl = w*32 + m*16 + lk*4 + r
        #pragma unroll
        for (int m=0;m<MT;++m)
            #pragma unroll
            for (int n=0;n<NT;++n){
                int co = n*16 + lrow;
                int grp = co>>3, cr = co&7;
                #pragma unroll
                for (int r=0;r<4;++r){
                    int pl = w*32 + m*16 + lk*4 + r;
                    sbuf[pl*64 + ((grp^(pl&7))<<3) + cr] = f2b(acc[m][n][r]);
                }
            }
        __syncthreads();
        if (t < 128){
            int pl = t;
            uint4 raw[8];
            float s = 0.f, ss = 0.f;
            #pragma unroll
            for (int j=0;j<8;++j){
                raw[j] = *(const uint4*)&sbuf[pl*64 + ((j^(pl&7))<<3)];
                float f[8]; up8(raw[j], f);
                #pragma unroll
                for (int k=0;k<8;++k){ s += f[k]; ss += f[k]*f[k]; }
            }
            float mu = s*(1.f/64.f);
            float rs = rsqrtf(ss*(1.f/64.f) - mu*mu + 1e-5f);
            const float* lw = sel ? lnw1 : lnw0;
            const float* lb = sel ? lnb1 : lnb0;
            unsigned short* out = (unsigned short*)(sel ? outB : outp);
            size_t p = (size_t)(y0+(pl>>6))*W_ + x0 + (pl&63);
            #pragma unroll
            for (int j=0;j<8;++j){
                float f[8], o[8];
                up8(raw[j], f);
                #pragma unroll
                for (int k=0;k<8;++k) o[k] = (f[k]-mu)*rs*lw[j*8+k] + lb[j*8+k];
                int cc = j*8;
                unsigned short* dst = out + ((size_t)b*2 + (cc>>5))*(size_t)HW_*32 + p*32 + (cc&31);
                *(uint4*)dst = pk8(o);
            }
        }
    } else {
        unsigned short* out = (unsigned short*)(sel ? outB : outp);
        #pragma unroll
        for (int m=0;m<MT;++m)
            #pragma unroll
            for (int n=0;n<NT;++n){
                int co = (KS==3) ? (n*16 + lrow) : (wx*(16*NT) + n*16 + lrow);
                #pragma unroll
                for (int r=0;r<4;++r){
                    int pl = (KS==3) ? (w*32 + m*16 + lk*4 + r) : (wy*64 + m*16 + lk*4 + r);
                    sbuf[pl*BN + co] = f2b(acc[m][n][r]);
                }
            }
        __syncthreads();
        for (int i=t; i<128*BN/8; i+=256){
            int pl = i/(BN/8), c8 = (i%(BN/8))*8;
            size_t p = (KS==3) ? ((size_t)(y0+(pl>>6))*W_ + (size_t)(x0+(pl&63))) : (p0+pl);
            int cc = cob + c8;
            unsigned short* dst = out + (size_t)b*HW_*so + ((size_t)(cc>>5)*HW_ + p)*32 + (cc&31);
            *(uint4*)dst = *(uint4*)&sbuf[pl*BN + c8];
        }
    }
}

// ---------------- channel LayerNorm (blocked bf16, coalesced, shfl group) ----------------
template<int C>
__global__ __launch_bounds__(256) void cln_k(unsigned short* __restrict__ io,
                                             const float* __restrict__ wg,
                                             const float* __restrict__ bi)
{
    constexpr int L = C/8;
    size_t idx = (size_t)blockIdx.x*256 + threadIdx.x;
    int sub = (int)(idx % L);
    size_t pix = idx / L;
    int b = (int)(pix >> 14);
    size_t p = pix & (HW_-1);
    unsigned short* rp = io + ((size_t)b*(C/32) + (sub>>2))*(size_t)HW_*32 + p*32 + (sub&3)*8;
    uint4 raw = *(const uint4*)rp;
    float f[8]; up8(raw, f);
    float s = 0.f, ss = 0.f;
    #pragma unroll
    for (int j=0;j<8;++j){ s += f[j]; ss += f[j]*f[j]; }
    #pragma unroll
    for (int m=1;m<L;m<<=1){ s += __shfl_xor(s,m); ss += __shfl_xor(ss,m); }
    float mu = s*(1.f/C);
    float rs = rsqrtf(ss*(1.f/C) - mu*mu + 1e-5f);
    float4 w0 = *(const float4*)(wg+sub*8), w1 = *(const float4*)(wg+sub*8+4);
    float4 b0 = *(const float4*)(bi+sub*8), b1 = *(const float4*)(bi+sub*8+4);
    float o[8];
    o[0]=(f[0]-mu)*rs*w0.x+b0.x; o[1]=(f[1]-mu)*rs*w0.y+b0.y;
    o[2]=(f[2]-mu)*rs*w0.z+b0.z; o[3]=(f[3]-mu)*rs*w0.w+b0.w;
    o[4]=(f[4]-mu)*rs*w1.x+b1.x; o[5]=(f[5]-mu)*rs*w1.y+b1.y;
    o[6]=(f[6]-mu)*rs*w1.z+b1.z; o[7]=(f[7]-mu)*rs*w1.w+b1.w;
    *(uint4*)rp = pk8(o);
}

// ---------------- depthwise 3x3 blocked bf16 (+GELU) ----------------
template<int CH, bool GELU>
__global__ __launch_bounds__(256) void dw_k(const unsigned short* __restrict__ in,
                                            const unsigned short* __restrict__ wp,
                                            unsigned short* __restrict__ out)
{
    size_t idx = (size_t)blockIdx.x*256 + threadIdx.x;
    int c8 = (int)(idx % (CH/8));
    size_t pix = idx / (CH/8);
    int p = (int)(pix % HW_);
    int b = (int)(pix / HW_);
    int yy = p >> 7, xx = p & 127;
    const unsigned short* ib = in + ((size_t)b*(CH/32) + (c8>>2))*(size_t)HW_*32 + (c8&3)*8;
    float wf[9][8];
    #pragma unroll
    for (int tap=0; tap<9; ++tap){
        uint4 r = *(const uint4*)(wp + tap*CH + c8*8);
        up8(r, wf[tap]);
    }
    float a[8] = {0,0,0,0,0,0,0,0};
    #pragma unroll
    for (int ky=0; ky<3; ++ky){
        int gy = yy+ky-1;
        if ((unsigned)gy >= (unsigned)H_) continue;
        #pragma unroll
        for (int kx=0; kx<3; ++kx){
            int gx = xx+kx-1;
            if ((unsigned)gx >= (unsigned)W_) continue;
            uint4 r = *(const uint4*)(ib + (size_t)(gy*W_+gx)*32);
            float f[8]; up8(r, f);
            #pragma unroll
            for (int j=0;j<8;++j) a[j] += f[j]*wf[ky*3+kx][j];
        }
    }
    if (GELU){
        #pragma unroll
        for (int j=0;j<8;++j) a[j] = 0.5f*a[j]*(1.f + erff(a[j]*0.70710678118654752f));
    }
    unsigned short* ob = out + ((size_t)b*(CH/32) + (c8>>2))*(size_t)HW_*32 + (size_t)p*32 + (c8&3)*8;
    *(uint4*)ob = pk8(a);
}

// ---------------- attention probs per (b,h) ----------------
__global__ __launch_bounds__(256) void attn_k(const unsigned short* __restrict__ qc,
                                              const unsigned short* __restrict__ kvd,
                                              const float* __restrict__ temp,
                                              float* __restrict__ probs)
{
    int b = blockIdx.x >> 3, h = blockIdx.x & 7;
    int t = threadIdx.x;
    const unsigned short* qb = qc  + ((size_t)b*2 + (h>>2))*(size_t)HW_*32 + (h&3)*8;
    const unsigned short* kb = kvd + ((size_t)b*4 + (h>>2))*(size_t)HW_*32 + (h&3)*8;
    float qs[8] = {}, ks[8] = {}, dt[8][8] = {{}};
    for (int p = t; p < HW_; p += 256){
        float qv[8], kv[8];
        up8(*(const uint4*)(qb + (size_t)p*32), qv);
        up8(*(const uint4*)(kb + (size_t)p*32), kv);
        #pragma unroll
        for (int i=0;i<8;++i){ qs[i]+=qv[i]*qv[i]; ks[i]+=kv[i]*kv[i]; }
        #pragma unroll
        for (int i=0;i<8;++i)
            #pragma unroll
            for (int j=0;j<8;++j) dt[i][j] += qv[i]*kv[j];
    }
    __shared__ float red[4][80];
    __shared__ float fin[80];
    int lane = t & 63, wv = t >> 6;
    #pragma unroll
    for (int i=0;i<8;++i){ float v=qs[i]; for (int m=1;m<64;m<<=1) v += __shfl_xor(v,m); if(!lane) red[wv][i]=v; }
    #pragma unroll
    for (int i=0;i<8;++i){ float v=ks[i]; for (int m=1;m<64;m<<=1) v += __shfl_xor(v,m); if(!lane) red[wv][8+i]=v; }
    #pragma unroll
    for (int i=0;i<8;++i)
        #pragma unroll
        for (int j=0;j<8;++j){ float v=dt[i][j]; for (int m=1;m<64;m<<=1) v += __shfl_xor(v,m); if(!lane) red[wv][16+i*8+j]=v; }
    __syncthreads();
    if (t < 80) fin[t] = red[0][t]+red[1][t]+red[2][t]+red[3][t];
    __syncthreads();
    if (t < 8){
        int i = t;
        float qn = fmaxf(sqrtf(fin[i]), 1e-12f);
        float tm = temp[h];
        float lg[8]; float mx = -1e30f;
        #pragma unroll
        for (int j=0;j<8;++j){
            float kn = fmaxf(sqrtf(fin[8+j]), 1e-12f);
            lg[j] = fin[16+i*8+j]/(qn*kn)*tm;
            mx = fmaxf(mx, lg[j]);
        }
        float se = 0.f;
        #pragma unroll
        for (int j=0;j<8;++j){ lg[j]=expf(lg[j]-mx); se+=lg[j]; }
        float inv = 1.f/se;
        #pragma unroll
        for (int j=0;j<8;++j) probs[(((size_t)b*8+h)*8+i)*8+j] = lg[j]*inv;
    }
}

// ---------------- Mb = w_po . blockdiag(attn)  [8][64][64] ----------------
__global__ __launch_bounds__(256) void mb_k(const float* __restrict__ probs,
                                            const float* __restrict__ wpo,
                                            float* __restrict__ Mb)
{
    int b = blockIdx.x;
    for (int o = threadIdx.x; o < 4096; o += 256){
        int co = o >> 6, d = o & 63, h = d >> 3, j = d & 7;
        float s = 0.f;
        #pragma unroll
        for (int i2=0;i2<8;++i2)
            s += wpo[co*64 + h*8 + i2] * probs[(((size_t)b*8+h)*8+i2)*8 + j];
        Mb[(size_t)b*4096 + o] = s;
    }
}

// ---------------- weff: per-batch expand weights, layout [coT][kb][tap][lane][8] ----------------
__global__ __launch_bounds__(256) void weff_k(const float* __restrict__ Mb,
                                              const float* __restrict__ wex,
                                              unsigned short* __restrict__ weff)
{
    int b = blockIdx.x / 576;
    int i = (blockIdx.x % 576)*256 + threadIdx.x;   // < 147456
    int ee = i & 7;
    int l  = (i>>3) & 63;
    int t2 = i >> 9;           // (coT*2 + kb)*9 + tap
    int tap = t2 % 9;
    int t3  = t2 / 9;
    int kb  = t3 & 1;
    int coT = t3 >> 1;
    int eo = coT*16 + (l & 15);
    int d  = kb*32 + (l >> 4)*8 + ee;
    const float* mb = Mb + (size_t)b*4096;
    float s = 0.f;
    #pragma unroll 8
    for (int c=0;c<64;++c)
        s += wex[(size_t)(eo*64+c)*9 + tap] * mb[c*64 + d];
    weff[(size_t)b*147456 + i] = f2b(s);
}

extern "C" void kernel_launch(void* const* d_in, const int* in_sizes, int n_in,
                              void* d_out, int out_size, void* d_ws, size_t ws_size,
                              hipStream_t stream) {
    (void)in_sizes; (void)n_in; (void)out_size; (void)ws_size;
    const float* x        = (const float*)d_in[0];
    const float* y        = (const float*)d_in[1];
    const float* w_cq     = (const float*)d_in[2];
    const float* w_ckv    = (const float*)d_in[3];
    const float* ln_q_w   = (const float*)d_in[4];
    const float* ln_q_b   = (const float*)d_in[5];
    const float* ln_kv_w  = (const float*)d_in[6];
    const float* ln_kv_b  = (const float*)d_in[7];
    const float* w_kv     = (const float*)d_in[8];
    const float* w_kvdw   = (const float*)d_in[9];
    const float* w_q      = (const float*)d_in[10];
    const float* temperature = (const float*)d_in[11];
    const float* w_po     = (const float*)d_in[12];
    const float* w_expand = (const float*)d_in[13];
    const float* ln_out_w = (const float*)d_in[14];
    const float* ln_out_b = (const float*)d_in[15];
    const float* w_ffn1   = (const float*)d_in[16];
    const float* w_ffn_dw = (const float*)d_in[17];
    const float* w_ffn2   = (const float*)d_in[18];
    float* outp = (float*)d_out;

    const size_t MB = 1u<<20;
    char* ws8 = (char*)d_ws;
    unsigned short* ykv  = (unsigned short*)(ws8 + 0);        // 16MB
    unsigned short* xq   = (unsigned short*)(ws8 + 16*MB);    // 16MB
    unsigned short* kv1  = (unsigned short*)(ws8 + 32*MB);    // 32MB
    unsigned short* qc   = (unsigned short*)(ws8 + 64*MB);    // 16MB
    unsigned short* kvd  = (unsigned short*)(ws8 + 80*MB);    // 32MB
    unsigned short* vexp = (unsigned short*)(ws8 + 0);        // 64MB
    unsigned short* f2b_ = (unsigned short*)(ws8 + 0);        // 64MB
    float* probs = (float*)(ws8 + 112*MB);
    float* Mb    = (float*)(ws8 + 113*MB);
    unsigned short* weff = (unsigned short*)(ws8 + 114*MB);   // 2.25MB
    unsigned short* wpB  = (unsigned short*)(ws8 + 117*MB);
    unsigned short* wp_cq  = wpB;
    unsigned short* wp_ckv = wpB + 147456;
    unsigned short* wp_q   = wpB + 294912;
    unsigned short* wp_kv  = wpB + 331776;
    unsigned short* wp_f1  = wpB + 339968;
    unsigned short* wp_f2  = wpB + 471040;
    unsigned short* wp_dwk = wpB + 536576;
    unsigned short* wp_dwf = wpB + 537728;
    unsigned short* zbuf   = wpB + 540032;
    unsigned short* xb = (unsigned short*)d_out;              // d_out[0,64MB)
    unsigned short* yb = (unsigned short*)d_out + 32*MB;      // d_out[64,128MB)
    unsigned short* f1 = yb;

    const unsigned short* NUL = (const unsigned short*)nullptr;

    prep_k<<<2111, 256, 0, stream>>>(w_cq, w_ckv, w_q, w_kv, w_ffn1, w_ffn2, w_kvdw, w_ffn_dw,
                                     wp_cq, wp_ckv, wp_q, wp_kv, wp_f1, wp_f2, wp_dwk, wp_dwf);
    pack_k<<<dim3(256,4,16), 256, 0, stream>>>(y, x, yb, xb);
    // fused cq+ckv with in-epilogue LayerNorm
    mconv_k<256,0,64,3,64,0,1><<<128*1*16, 256, 0, stream>>>(yb,256, NUL,0, wp_ckv,0, ykv,64,
        xb, wp_cq, xq, zbuf, ln_kv_w, ln_kv_b, ln_q_w, ln_q_b, 1, 16);
    // kv1: BN=128 (full COUT in one block-col)
    mconv_k<64,0,128,1,128,0,0><<<128*1*8, 256, 0, stream>>>(ykv,64, NUL,0, wp_kv,0, kv1,128,
        ykv, wp_kv, kv1, zbuf, NULL,NULL,NULL,NULL, 1, 8);
    mconv_k<64,0,64,3,64,0,0><<<128*1*8, 256, 0, stream>>>(xq,64, NUL,0, wp_q,0, qc,64,
        xq, wp_q, qc, zbuf, NULL,NULL,NULL,NULL, 1, 8);
    dw_k<128,false><<<8192, 256, 0, stream>>>(kv1, wp_dwk, kvd);
    attn_k<<<64, 256, 0, stream>>>(qc, kvd, temperature, probs);
    mb_k<<<8, 256, 0, stream>>>(probs, w_po, Mb);
    weff_k<<<4608, 256, 0, stream>>>(Mb, w_expand, weff);
    // fused attn@v + project_out + expand; v = planes 2,3 of kvd
    mconv_k<64,0,256,3,64,0,0><<<128*4*8, 256, 0, stream>>>(kvd + (size_t)HW_*64,128, NUL,0, weff,147456, vexp,256,
        kvd + (size_t)HW_*64, weff, vexp, zbuf, NULL,NULL,NULL,NULL, 4, 8);
    cln_k<256><<<16384, 256, 0, stream>>>(vexp, ln_out_w, ln_out_b);
    // ffn1: BN=128
    mconv_k<256,256,256,1,128,0,0><<<128*2*8, 256, 0, stream>>>(xb,256, vexp,256, wp_f1,0, f1,256,
        xb, wp_f1, f1, zbuf, NULL,NULL,NULL,NULL, 2, 8);
    dw_k<256,true><<<16384, 256, 0, stream>>>(f1, wp_dwf, f2b_);
    // ffn2: BN=128, fp32 NCHW output via LDS transpose (two co-half passes)
    mconv_k<256,0,256,1,128,1,0><<<128*2*8, 256, 0, stream>>>(f2b_,256, NUL,0, wp_f2,0, outp,0,
        f2b_, wp_f2, outp, zbuf, NULL,NULL,NULL,NULL, 2, 8);
}

// Round 14
// 494.352 us; speedup vs baseline: 1.1308x; 1.1308x over previous
//
#include <hip/hip_runtime.h>
#include <hip/hip_bf16.h>
#include <math.h>

#define B_ 8
#define C_ 256
#define S_ 64
#define H_ 128
#define W_ 128
#define HW_ (H_*W_)
#define P_ (B_*HW_)

typedef __attribute__((ext_vector_type(8))) short short8;
typedef __attribute__((ext_vector_type(4))) float f32x4;

__device__ __forceinline__ unsigned short f2b(float f){
    __hip_bfloat16 h = __float2bfloat16(f);
    return *reinterpret_cast<unsigned short*>(&h);
}
__device__ __forceinline__ void up8(uint4 u, float* f){
    unsigned v0=u.x,v1=u.y,v2=u.z,v3=u.w;
    f[0]=__uint_as_float(v0<<16); f[1]=__uint_as_float(v0&0xffff0000u);
    f[2]=__uint_as_float(v1<<16); f[3]=__uint_as_float(v1&0xffff0000u);
    f[4]=__uint_as_float(v2<<16); f[5]=__uint_as_float(v2&0xffff0000u);
    f[6]=__uint_as_float(v3<<16); f[7]=__uint_as_float(v3&0xffff0000u);
}
__device__ __forceinline__ uint4 pk8(const float* f){
    uint4 u;
    u.x = (unsigned)f2b(f[0]) | ((unsigned)f2b(f[1])<<16);
    u.y = (unsigned)f2b(f[2]) | ((unsigned)f2b(f[3])<<16);
    u.z = (unsigned)f2b(f[4]) | ((unsigned)f2b(f[5])<<16);
    u.w = (unsigned)f2b(f[6]) | ((unsigned)f2b(f[7])<<16);
    return u;
}
__device__ __forceinline__ void gl2lds(const unsigned short* g, unsigned short* l){
    __builtin_amdgcn_global_load_lds((const __attribute__((address_space(1))) void*)g,
                                     (__attribute__((address_space(3))) void*)l, 16, 0, 0);
}

// All activations use C32-blocked layout: [b][C/32][HW][32] (bf16).

// ---------------- NCHW fp32 -> blocked bf16 pack (fused x+y via z) ----------------
__global__ __launch_bounds__(256) void pack_k(const float* __restrict__ inA,
                                              const float* __restrict__ inB,
                                              unsigned short* __restrict__ outA,
                                              unsigned short* __restrict__ outB)
{
    __shared__ unsigned short tl[64][72];
    const int t = threadIdx.x;
    const int p0 = blockIdx.x*64, c0 = blockIdx.y*64;
    const int sel = blockIdx.z >> 3, b = blockIdx.z & 7;
    const float* in = sel ? inB : inA;
    unsigned short* out = sel ? outB : outA;
    const float* ib = in + ((size_t)b*C_ + c0)*HW_ + p0;
    for (int i = t; i < 1024; i += 256){
        int ci = i >> 4, px = (i & 15)*4;
        float4 v = *(const float4*)(ib + (size_t)ci*HW_ + px);
        tl[px+0][ci]=f2b(v.x); tl[px+1][ci]=f2b(v.y); tl[px+2][ci]=f2b(v.z); tl[px+3][ci]=f2b(v.w);
    }
    __syncthreads();
    for (int i = t; i < 512; i += 256){
        int px = i >> 3, c8 = (i & 7)*8;
        int cc = c0 + c8;
        unsigned short* dst = out + ((size_t)b*8 + (cc>>5))*(size_t)HW_*32
                                  + (size_t)(p0+px)*32 + (cc&31);
        *(uint4*)dst = *(uint4*)&tl[px][c8];
    }
}

// ---------------- weight prepack: fragment-major [coT][kb][tap][lane][8] ----------------
__device__ __forceinline__ void packw(const float* __restrict__ src, unsigned short* __restrict__ dst,
                                      int e, int CO, int CI, int TAPS)
{
    int KB = CI/32;
    int ee = e & 7;
    int l  = (e>>3) & 63;
    int t2 = e >> 9;            // (coT*KB + kb)*TAPS + tap
    int tap = t2 % TAPS;
    int t3  = t2 / TAPS;        // coT*KB + kb
    int kb  = t3 % KB;
    int coT = t3 / KB;
    int co = coT*16 + (l & 15);
    int ci = kb*32 + (l >> 4)*8 + ee;
    float v = (TAPS==9) ? src[(size_t)(co*CI+ci)*9 + tap] : src[(size_t)co*CI + ci];
    dst[e] = f2b(v);
}

__global__ __launch_bounds__(256) void prep_k(const float* __restrict__ cq, const float* __restrict__ ckv,
                                              const float* __restrict__ q,  const float* __restrict__ kv,
                                              const float* __restrict__ f1, const float* __restrict__ f2,
                                              const float* __restrict__ dwk, const float* __restrict__ dwf,
                                              unsigned short* o_cq, unsigned short* o_ckv, unsigned short* o_q,
                                              unsigned short* o_kv, unsigned short* o_f1, unsigned short* o_f2,
                                              unsigned short* o_dwk, unsigned short* o_dwf)
{
    int i = blockIdx.x*256 + threadIdx.x;
    if      (i < 147456) packw(cq,  o_cq,  i,          64, 256, 9);
    else if (i < 294912) packw(ckv, o_ckv, i-147456,   64, 256, 9);
    else if (i < 331776) packw(q,   o_q,   i-294912,   64,  64, 9);
    else if (i < 339968) packw(kv,  o_kv,  i-331776,  128,  64, 1);
    else if (i < 471040) packw(f1,  o_f1,  i-339968,  256, 512, 1);
    else if (i < 536576) packw(f2,  o_f2,  i-471040,  256, 256, 1);
    else if (i < 537728) { int e=i-536576; o_dwk[e] = f2b(dwk[(e&127)*9 + (e>>7)]); }
    else if (i < 540032) { int e=i-537728; o_dwf[e] = f2b(dwf[(e&255)*9 + (e>>8)]); }
    else if (i < 540040) { o_dwf[i-537728] = 0; }   // 16B zero page for OOB halo
}

// ---------------- MFMA conv: BM=128, BN=64/128, 4 waves 2Mx2N; hoisted addressing ----------------
// (round-11 empirical optimum: KS3 MT4/NT2 @4blk/CU, KS1 BN=128 @3blk/CU)
template<int C0,int C1,int COUT,int KS,int BN,int OUTM,int LNF>
__global__ __launch_bounds__(256, (BN==128)?3:4) void mconv_k(
    const unsigned short* __restrict__ in0, int s0,
    const unsigned short* __restrict__ in1, int s1,
    const unsigned short* __restrict__ wp, long wpbs,
    void* __restrict__ outp, int so,
    const unsigned short* __restrict__ in0B,
    const unsigned short* __restrict__ wpB2,
    void* __restrict__ outB,
    const unsigned short* __restrict__ zbuf,
    const float* __restrict__ lnw0, const float* __restrict__ lnb0,
    const float* __restrict__ lnw1, const float* __restrict__ lnb1,
    int ny, int nz)
{
    constexpr int CINT = C0+C1;
    constexpr int KB   = CINT/32;
    constexpr int KB0  = C0/32;
    constexpr int TAPS = KS*KS;
    constexpr int MT  = 4;
    constexpr int NT  = BN/32;
    constexpr int PXS = (KS==3)?66:128;
    constexpr int ASZ = (KS==3)? 4*66*32 : 8192;     // shorts per buffer
    constexpr int EP  = (OUTM==1) ? 64*132*2 : 128*BN;
    constexpr int SSZ = (2*ASZ > EP) ? 2*ASZ : EP;
    __shared__ alignas(16) unsigned short sbuf[SSZ];

    const int t = threadIdx.x;
    const int nper = (128*ny*nz) >> 3;
    int lin = (blockIdx.x & 7)*nper + (blockIdx.x >> 3);
    const int gy_ = lin % ny;
    int rem = lin / ny;
    const int gx_ = rem & 127;
    const int gz_ = rem >> 7;
    const int sel = gz_ >> 3;
    const int b   = gz_ & 7;
    const int cob = gy_*BN;

    const unsigned short* pin0 = sel ? in0B : in0;
    const unsigned short* wpb  = (sel ? wpB2 : wp) + (size_t)b*wpbs;

    int y0=0,x0=0; size_t p0=0;
    if (KS==3){ y0=(gx_>>1)*2; x0=(gx_&1)*64; }
    else p0 = (size_t)gx_*128;

    const int l = t&63, w = t>>6;
    const int wy = w>>1, wx = w&1;
    const int lrow = l&15, lk = l>>4;

    const size_t b0base = (size_t)b*HW_*s0;
    const size_t b1base = (size_t)b*HW_*s1;
    const size_t KSTEP = (size_t)HW_*32;             // per-kb source stride

    // ---- hoisted B bases: fragment (coT,kb,tap) at ((coT*KB+kb)*TAPS+tap)*512 ----
    const unsigned short* pB[NT];
    #pragma unroll
    for (int n=0;n<NT;++n)
        pB[n] = wpb + (size_t)((cob>>4) + wx*NT + n)*KB*TAPS*512 + l*8;
    auto loadB = [&](short8* dst, int kb, int tap){
        #pragma unroll
        for (int n=0;n<NT;++n)
            dst[n] = *(const short8*)(pB[n] + (size_t)(kb*TAPS+tap)*512);
    };

    f32x4 acc[MT][NT] = {};

    if (KS==3){
        // ---- hoisted A bases (C1==0 on all KS3 launches) ----
        const unsigned short* aptr[5]; bool aok[5];
        #pragma unroll
        for (int j=0;j<5;++j){
            int i = t + j*256;
            if (j<4 || i<1056){
                int slot=i&3, pr=i>>2;
                int px=pr%66, row=pr/66;
                int g = slot ^ (px&3) ^ ((px>>2)&3);
                int gy=y0+row-1, gx=x0+px-1;
                aok[j] = ((unsigned)gy<(unsigned)H_) & ((unsigned)gx<(unsigned)W_);
                size_t p=(size_t)gy*W_+gx;
                aptr[j] = pin0 + b0base + p*32 + g*8;
            }
        }
        auto issueA3 = [&](int kb, int bsel){
            unsigned short* dst = sbuf + bsel*ASZ;
            size_t kof = (size_t)kb*KSTEP;
            #pragma unroll
            for (int j=0;j<5;++j){
                int i = t + j*256;
                if (j<4 || i<1056){
                    const unsigned short* s = aok[j] ? aptr[j] + kof : zbuf;
                    gl2lds(s, dst + (size_t)i*8);
                }
            }
        };

        short8 bfs[3][NT];
        issueA3(0,0);
        loadB(bfs[0],0,0); loadB(bfs[1],0,1); loadB(bfs[2],0,2);
        for (int kb=0; kb<KB; ++kb){
            __syncthreads();
            if (kb+1<KB) issueA3(kb+1,(kb+1)&1);
            unsigned short* cur = sbuf + (kb&1)*ASZ;
            #pragma unroll
            for (int tap=0;tap<9;++tap){
                const int ky=tap/3, kx=tap%3;
                short8 af[MT];
                #pragma unroll
                for (int m=0;m<MT;++m){
                    int pl = wy*64 + m*16 + lrow;
                    int r = (pl>>6)+ky, xx = (pl&63)+kx;
                    af[m] = *(const short8*)&cur[((r*PXS+xx)*4 + (lk^(xx&3)^((xx>>2)&3)))*8];
                }
                #pragma unroll
                for (int m=0;m<MT;++m)
                    #pragma unroll
                    for (int n=0;n<NT;++n)
                        acc[m][n] = __builtin_amdgcn_mfma_f32_16x16x32_bf16(af[m],bfs[tap%3][n],acc[m][n],0,0,0);
                if (tap+3 < 9)      loadB(bfs[tap%3], kb, tap+3);
                else if (kb+1<KB)   loadB(bfs[tap%3], kb+1, tap-6);
            }
        }
    } else {
        // ---- hoisted A bases (two inputs for concat) ----
        const unsigned short* a0[2]; const unsigned short* a1[2];
        #pragma unroll
        for (int j=0;j<2;++j){
            int i = t + j*256;
            int slot=i&3, px=i>>2;
            int g = slot ^ (px&3) ^ ((px>>2)&3);
            size_t p = p0+px;
            a0[j] = pin0 + b0base + p*32 + g*8;
            a1[j] = in1  + b1base + p*32 + g*8;
        }
        auto issueA1 = [&](int s, int bsel){
            unsigned short* dst = sbuf + bsel*ASZ;
            #pragma unroll
            for (int h=0;h<2;++h){
                const int kb = s*2+h;
                #pragma unroll
                for (int j=0;j<2;++j){
                    int i = t + j*256;
                    const unsigned short* sp;
                    if (C1==0 || kb < KB0) sp = a0[j] + (size_t)kb*KSTEP;
                    else                   sp = a1[j] + (size_t)(kb-KB0)*KSTEP;
                    gl2lds(sp, dst + (size_t)(h*4096 + i*8));
                }
            }
        };

        constexpr int KBS = (KB>=2) ? KB/2 : 1;
        short8 bfs[2][NT];
        issueA1(0,0);
        loadB(bfs[0],0,0); loadB(bfs[1],1,0);
        for (int s=0; s<KBS; ++s){
            __syncthreads();
            if (s+1<KBS) issueA1(s+1,(s+1)&1);
            unsigned short* cur = sbuf + (s&1)*ASZ;
            #pragma unroll
            for (int j=0;j<2;++j){
                short8 af[MT];
                #pragma unroll
                for (int m=0;m<MT;++m){
                    int pl = wy*64 + m*16 + lrow;
                    af[m] = *(const short8*)&cur[j*4096 + (pl*4 + (lk^(pl&3)^((pl>>2)&3)))*8];
                }
                #pragma unroll
                for (int m=0;m<MT;++m)
                    #pragma unroll
                    for (int n=0;n<NT;++n)
                        acc[m][n] = __builtin_amdgcn_mfma_f32_16x16x32_bf16(af[m],bfs[j][n],acc[m][n],0,0,0);
                if (s*2+j+2 < KB) loadB(bfs[j], s*2+j+2, 0);
            }
        }
    }
    __syncthreads();

    if (OUTM==1){
        // fp32 NCHW out via LDS transpose; BN=128: two co-half passes (wave wx==h owns half h)
        float* sf = (float*)sbuf;
        float* out = (float*)(sel ? outB : outp);
        #pragma unroll
        for (int h=0; h<BN/64; ++h){
            if (h) __syncthreads();
            if (BN==64 || wx==h){
                #pragma unroll
                for (int m=0;m<MT;++m)
                    #pragma unroll
                    for (int n=0;n<NT;++n){
                        int co_l = (BN==64 ? wx*32 : 0) + n*16 + lrow;
                        int pl0  = wy*64 + m*16 + lk*4;
                        *(f32x4*)&sf[co_l*132 + pl0] = acc[m][n];
                    }
            }
            __syncthreads();
            for (int i=t; i<2048; i+=256){
                int co = i>>5, pxg = i&31;
                f32x4 v = *(const f32x4*)&sf[co*132 + pxg*4];
                *(f32x4*)(out + ((size_t)(b*COUT + cob + h*64 + co))*HW_ + p0 + pxg*4) = v;
            }
        }
    } else if (LNF){
        #pragma unroll
        for (int m=0;m<MT;++m)
            #pragma unroll
            for (int n=0;n<NT;++n){
                int co = wx*(16*NT) + n*16 + lrow;
                int grp = co>>3, cr = co&7;
                #pragma unroll
                for (int r=0;r<4;++r){
                    int pl = wy*64 + m*16 + lk*4 + r;
                    sbuf[pl*64 + ((grp^(pl&7))<<3) + cr] = f2b(acc[m][n][r]);
                }
            }
        __syncthreads();
        if (t < 128){
            int pl = t;
            uint4 raw[8];
            float s = 0.f, ss = 0.f;
            #pragma unroll
            for (int j=0;j<8;++j){
                raw[j] = *(const uint4*)&sbuf[pl*64 + ((j^(pl&7))<<3)];
                float f[8]; up8(raw[j], f);
                #pragma unroll
                for (int k=0;k<8;++k){ s += f[k]; ss += f[k]*f[k]; }
            }
            float mu = s*(1.f/64.f);
            float rs = rsqrtf(ss*(1.f/64.f) - mu*mu + 1e-5f);
            const float* lw = sel ? lnw1 : lnw0;
            const float* lb = sel ? lnb1 : lnb0;
            unsigned short* out = (unsigned short*)(sel ? outB : outp);
            size_t p = (size_t)(y0+(pl>>6))*W_ + x0 + (pl&63);
            #pragma unroll
            for (int j=0;j<8;++j){
                float f[8], o[8];
                up8(raw[j], f);
                #pragma unroll
                for (int k=0;k<8;++k) o[k] = (f[k]-mu)*rs*lw[j*8+k] + lb[j*8+k];
                int cc = j*8;
                unsigned short* dst = out + ((size_t)b*2 + (cc>>5))*(size_t)HW_*32 + p*32 + (cc&31);
                *(uint4*)dst = pk8(o);
            }
        }
    } else {
        unsigned short* out = (unsigned short*)(sel ? outB : outp);
        #pragma unroll
        for (int m=0;m<MT;++m)
            #pragma unroll
            for (int n=0;n<NT;++n){
                int co = wx*(16*NT) + n*16 + lrow;
                #pragma unroll
                for (int r=0;r<4;++r){
                    int pl = wy*64 + m*16 + lk*4 + r;
                    sbuf[pl*BN + co] = f2b(acc[m][n][r]);
                }
            }
        __syncthreads();
        for (int i=t; i<128*BN/8; i+=256){
            int pl = i/(BN/8), c8 = (i%(BN/8))*8;
            size_t p = (KS==3) ? ((size_t)(y0+(pl>>6))*W_ + (size_t)(x0+(pl&63))) : (p0+pl);
            int cc = cob + c8;
            unsigned short* dst = out + (size_t)b*HW_*so + ((size_t)(cc>>5)*HW_ + p)*32 + (cc&31);
            *(uint4*)dst = *(uint4*)&sbuf[pl*BN + c8];
        }
    }
}

// ---------------- channel LayerNorm (blocked bf16, coalesced, shfl group) ----------------
template<int C>
__global__ __launch_bounds__(256) void cln_k(unsigned short* __restrict__ io,
                                             const float* __restrict__ wg,
                                             const float* __restrict__ bi)
{
    constexpr int L = C/8;
    size_t idx = (size_t)blockIdx.x*256 + threadIdx.x;
    int sub = (int)(idx % L);
    size_t pix = idx / L;
    int b = (int)(pix >> 14);
    size_t p = pix & (HW_-1);
    unsigned short* rp = io + ((size_t)b*(C/32) + (sub>>2))*(size_t)HW_*32 + p*32 + (sub&3)*8;
    uint4 raw = *(const uint4*)rp;
    float f[8]; up8(raw, f);
    float s = 0.f, ss = 0.f;
    #pragma unroll
    for (int j=0;j<8;++j){ s += f[j]; ss += f[j]*f[j]; }
    #pragma unroll
    for (int m=1;m<L;m<<=1){ s += __shfl_xor(s,m); ss += __shfl_xor(ss,m); }
    float mu = s*(1.f/C);
    float rs = rsqrtf(ss*(1.f/C) - mu*mu + 1e-5f);
    float4 w0 = *(const float4*)(wg+sub*8), w1 = *(const float4*)(wg+sub*8+4);
    float4 b0 = *(const float4*)(bi+sub*8), b1 = *(const float4*)(bi+sub*8+4);
    float o[8];
    o[0]=(f[0]-mu)*rs*w0.x+b0.x; o[1]=(f[1]-mu)*rs*w0.y+b0.y;
    o[2]=(f[2]-mu)*rs*w0.z+b0.z; o[3]=(f[3]-mu)*rs*w0.w+b0.w;
    o[4]=(f[4]-mu)*rs*w1.x+b1.x; o[5]=(f[5]-mu)*rs*w1.y+b1.y;
    o[6]=(f[6]-mu)*rs*w1.z+b1.z; o[7]=(f[7]-mu)*rs*w1.w+b1.w;
    *(uint4*)rp = pk8(o);
}

// ---------------- depthwise 3x3 blocked bf16 (+GELU) ----------------
template<int CH, bool GELU>
__global__ __launch_bounds__(256) void dw_k(const unsigned short* __restrict__ in,
                                            const unsigned short* __restrict__ wp,
                                            unsigned short* __restrict__ out)
{
    size_t idx = (size_t)blockIdx.x*256 + threadIdx.x;
    int c8 = (int)(idx % (CH/8));
    size_t pix = idx / (CH/8);
    int p = (int)(pix % HW_);
    int b = (int)(pix / HW_);
    int yy = p >> 7, xx = p & 127;
    const unsigned short* ib = in + ((size_t)b*(CH/32) + (c8>>2))*(size_t)HW_*32 + (c8&3)*8;
    float wf[9][8];
    #pragma unroll
    for (int tap=0; tap<9; ++tap){
        uint4 r = *(const uint4*)(wp + tap*CH + c8*8);
        up8(r, wf[tap]);
    }
    float a[8] = {0,0,0,0,0,0,0,0};
    #pragma unroll
    for (int ky=0; ky<3; ++ky){
        int gy = yy+ky-1;
        if ((unsigned)gy >= (unsigned)H_) continue;
        #pragma unroll
        for (int kx=0; kx<3; ++kx){
            int gx = xx+kx-1;
            if ((unsigned)gx >= (unsigned)W_) continue;
            uint4 r = *(const uint4*)(ib + (size_t)(gy*W_+gx)*32);
            float f[8]; up8(r, f);
            #pragma unroll
            for (int j=0;j<8;++j) a[j] += f[j]*wf[ky*3+kx][j];
        }
    }
    if (GELU){
        #pragma unroll
        for (int j=0;j<8;++j) a[j] = 0.5f*a[j]*(1.f + erff(a[j]*0.70710678118654752f));
    }
    unsigned short* ob = out + ((size_t)b*(CH/32) + (c8>>2))*(size_t)HW_*32 + (size_t)p*32 + (c8&3)*8;
    *(uint4*)ob = pk8(a);
}

// ---------------- attention stage 1: partial sums per (b,h,chunk) ----------------
// grid 1024 = 64 (b,h) x 16 chunks; each block reduces 1024 pixels -> 80 partials
__global__ __launch_bounds__(256) void attn1_k(const unsigned short* __restrict__ qc,
                                               const unsigned short* __restrict__ kvd,
                                               float* __restrict__ part)
{
    int bh = blockIdx.x >> 4, chunk = blockIdx.x & 15;
    int b = bh >> 3, h = bh & 7;
    int t = threadIdx.x;
    const unsigned short* qb = qc  + ((size_t)b*2 + (h>>2))*(size_t)HW_*32 + (h&3)*8;
    const unsigned short* kb = kvd + ((size_t)b*4 + (h>>2))*(size_t)HW_*32 + (h&3)*8;
    float qs[8] = {}, ks[8] = {}, dt[8][8] = {{}};
    for (int p = chunk*1024 + t; p < (chunk+1)*1024; p += 256){
        float qv[8], kv[8];
        up8(*(const uint4*)(qb + (size_t)p*32), qv);
        up8(*(const uint4*)(kb + (size_t)p*32), kv);
        #pragma unroll
        for (int i=0;i<8;++i){ qs[i]+=qv[i]*qv[i]; ks[i]+=kv[i]*kv[i]; }
        #pragma unroll
        for (int i=0;i<8;++i)
            #pragma unroll
            for (int j=0;j<8;++j) dt[i][j] += qv[i]*kv[j];
    }
    __shared__ float red[4][80];
    int lane = t & 63, wv = t >> 6;
    #pragma unroll
    for (int i=0;i<8;++i){ float v=qs[i]; for (int m=1;m<64;m<<=1) v += __shfl_xor(v,m); if(!lane) red[wv][i]=v; }
    #pragma unroll
    for (int i=0;i<8;++i){ float v=ks[i]; for (int m=1;m<64;m<<=1) v += __shfl_xor(v,m); if(!lane) red[wv][8+i]=v; }
    #pragma unroll
    for (int i=0;i<8;++i)
        #pragma unroll
        for (int j=0;j<8;++j){ float v=dt[i][j]; for (int m=1;m<64;m<<=1) v += __shfl_xor(v,m); if(!lane) red[wv][16+i*8+j]=v; }
    __syncthreads();
    if (t < 80) part[(size_t)blockIdx.x*80 + t] = red[0][t]+red[1][t]+red[2][t]+red[3][t];
}

// ---------------- attention stage 2: finalize softmax per (b,h) ----------------
__global__ __launch_bounds__(128) void attn2_k(const float* __restrict__ part,
                                               const float* __restrict__ temp,
                                               float* __restrict__ probs)
{
    int bh = blockIdx.x;
    int t = threadIdx.x;
    __shared__ float fin[80];
    if (t < 80){
        float s = 0.f;
        #pragma unroll
        for (int c=0;c<16;++c) s += part[(size_t)(bh*16+c)*80 + t];
        fin[t] = s;
    }
    __syncthreads();
    if (t < 8){
        int b = bh >> 3, h = bh & 7;
        int i = t;
        float qn = fmaxf(sqrtf(fin[i]), 1e-12f);
        float tm = temp[h];
        float lg[8]; float mx = -1e30f;
        #pragma unroll
        for (int j=0;j<8;++j){
            float kn = fmaxf(sqrtf(fin[8+j]), 1e-12f);
            lg[j] = fin[16+i*8+j]/(qn*kn)*tm;
            mx = fmaxf(mx, lg[j]);
        }
        float se = 0.f;
        #pragma unroll
        for (int j=0;j<8;++j){ lg[j]=expf(lg[j]-mx); se+=lg[j]; }
        float inv = 1.f/se;
        #pragma unroll
        for (int j=0;j<8;++j) probs[(((size_t)b*8+h)*8+i)*8+j] = lg[j]*inv;
    }
}

// ---------------- Mb = w_po . blockdiag(attn)  [8][64][64] ----------------
__global__ __launch_bounds__(256) void mb_k(const float* __restrict__ probs,
                                            const float* __restrict__ wpo,
                                            float* __restrict__ Mb)
{
    int b = blockIdx.x;
    for (int o = threadIdx.x; o < 4096; o += 256){
        int co = o >> 6, d = o & 63, h = d >> 3, j = d & 7;
        float s = 0.f;
        #pragma unroll
        for (int i2=0;i2<8;++i2)
            s += wpo[co*64 + h*8 + i2] * probs[(((size_t)b*8+h)*8+i2)*8 + j];
        Mb[(size_t)b*4096 + o] = s;
    }
}

// ---------------- weff: per-batch expand weights, layout [coT][kb][tap][lane][8] ----------------
__global__ __launch_bounds__(256) void weff_k(const float* __restrict__ Mb,
                                              const float* __restrict__ wex,
                                              unsigned short* __restrict__ weff)
{
    int b = blockIdx.x / 576;
    int i = (blockIdx.x % 576)*256 + threadIdx.x;   // < 147456
    int ee = i & 7;
    int l  = (i>>3) & 63;
    int t2 = i >> 9;           // (coT*2 + kb)*9 + tap
    int tap = t2 % 9;
    int t3  = t2 / 9;
    int kb  = t3 & 1;
    int coT = t3 >> 1;
    int eo = coT*16 + (l & 15);
    int d  = kb*32 + (l >> 4)*8 + ee;
    const float* mb = Mb + (size_t)b*4096;
    float s = 0.f;
    #pragma unroll 8
    for (int c=0;c<64;++c)
        s += wex[(size_t)(eo*64+c)*9 + tap] * mb[c*64 + d];
    weff[(size_t)b*147456 + i] = f2b(s);
}

extern "C" void kernel_launch(void* const* d_in, const int* in_sizes, int n_in,
                              void* d_out, int out_size, void* d_ws, size_t ws_size,
                              hipStream_t stream) {
    (void)in_sizes; (void)n_in; (void)out_size; (void)ws_size;
    const float* x        = (const float*)d_in[0];
    const float* y        = (const float*)d_in[1];
    const float* w_cq     = (const float*)d_in[2];
    const float* w_ckv    = (const float*)d_in[3];
    const float* ln_q_w   = (const float*)d_in[4];
    const float* ln_q_b   = (const float*)d_in[5];
    const float* ln_kv_w  = (const float*)d_in[6];
    const float* ln_kv_b  = (const float*)d_in[7];
    const float* w_kv     = (const float*)d_in[8];
    const float* w_kvdw   = (const float*)d_in[9];
    const float* w_q      = (const float*)d_in[10];
    const float* temperature = (const float*)d_in[11];
    const float* w_po     = (const float*)d_in[12];
    const float* w_expand = (const float*)d_in[13];
    const float* ln_out_w = (const float*)d_in[14];
    const float* ln_out_b = (const float*)d_in[15];
    const float* w_ffn1   = (const float*)d_in[16];
    const float* w_ffn_dw = (const float*)d_in[17];
    const float* w_ffn2   = (const float*)d_in[18];
    float* outp = (float*)d_out;

    const size_t MB = 1u<<20;
    char* ws8 = (char*)d_ws;
    unsigned short* ykv  = (unsigned short*)(ws8 + 0);        // 16MB
    unsigned short* xq   = (unsigned short*)(ws8 + 16*MB);    // 16MB
    unsigned short* kv1  = (unsigned short*)(ws8 + 32*MB);    // 32MB
    unsigned short* qc   = (unsigned short*)(ws8 + 64*MB);    // 16MB
    unsigned short* kvd  = (unsigned short*)(ws8 + 80*MB);    // 32MB
    unsigned short* vexp = (unsigned short*)(ws8 + 0);        // 64MB
    unsigned short* f2b_ = (unsigned short*)(ws8 + 0);        // 64MB
    float* probs = (float*)(ws8 + 112*MB);
    float* Mb    = (float*)(ws8 + 113*MB);
    unsigned short* weff = (unsigned short*)(ws8 + 114*MB);   // 2.25MB
    unsigned short* wpB  = (unsigned short*)(ws8 + 117*MB);
    unsigned short* wp_cq  = wpB;
    unsigned short* wp_ckv = wpB + 147456;
    unsigned short* wp_q   = wpB + 294912;
    unsigned short* wp_kv  = wpB + 331776;
    unsigned short* wp_f1  = wpB + 339968;
    unsigned short* wp_f2  = wpB + 471040;
    unsigned short* wp_dwk = wpB + 536576;
    unsigned short* wp_dwf = wpB + 537728;
    unsigned short* zbuf   = wpB + 540032;
    float* part = (float*)(ws8 + 119*MB);                     // 320KB attn partials
    unsigned short* xb = (unsigned short*)d_out;              // d_out[0,64MB)
    unsigned short* yb = (unsigned short*)d_out + 32*MB;      // d_out[64,128MB)
    unsigned short* f1 = yb;

    const unsigned short* NUL = (const unsigned short*)nullptr;

    prep_k<<<2111, 256, 0, stream>>>(w_cq, w_ckv, w_q, w_kv, w_ffn1, w_ffn2, w_kvdw, w_ffn_dw,
                                     wp_cq, wp_ckv, wp_q, wp_kv, wp_f1, wp_f2, wp_dwk, wp_dwf);
    pack_k<<<dim3(256,4,16), 256, 0, stream>>>(y, x, yb, xb);
    // fused cq+ckv with in-epilogue LayerNorm
    mconv_k<256,0,64,3,64,0,1><<<128*1*16, 256, 0, stream>>>(yb,256, NUL,0, wp_ckv,0, ykv,64,
        xb, wp_cq, xq, zbuf, ln_kv_w, ln_kv_b, ln_q_w, ln_q_b, 1, 16);
    // kv1: BN=128 (full COUT in one block-col)
    mconv_k<64,0,128,1,128,0,0><<<128*1*8, 256, 0, stream>>>(ykv,64, NUL,0, wp_kv,0, kv1,128,
        ykv, wp_kv, kv1, zbuf, NULL,NULL,NULL,NULL, 1, 8);
    mconv_k<64,0,64,3,64,0,0><<<128*1*8, 256, 0, stream>>>(xq,64, NUL,0, wp_q,0, qc,64,
        xq, wp_q, qc, zbuf, NULL,NULL,NULL,NULL, 1, 8);
    dw_k<128,false><<<8192, 256, 0, stream>>>(kv1, wp_dwk, kvd);
    // attention: two-stage (1024-block partial reduce + 64-block finalize)
    attn1_k<<<1024, 256, 0, stream>>>(qc, kvd, part);
    attn2_k<<<64, 128, 0, stream>>>(part, temperature, probs);
    mb_k<<<8, 256, 0, stream>>>(probs, w_po, Mb);
    weff_k<<<4608, 256, 0, stream>>>(Mb, w_expand, weff);
    // fused attn@v + project_out + expand; v = planes 2,3 of kvd
    mconv_k<64,0,256,3,64,0,0><<<128*4*8, 256, 0, stream>>>(kvd + (size_t)HW_*64,128, NUL,0, weff,147456, vexp,256,
        kvd + (size_t)HW_*64, weff, vexp, zbuf, NULL,NULL,NULL,NULL, 4, 8);
    cln_k<256><<<16384, 256, 0, stream>>>(vexp, ln_out_w, ln_out_b);
    // ffn1: BN=128
    mconv_k<256,256,256,1,128,0,0><<<128*2*8, 256, 0, stream>>>(xb,256, vexp,256, wp_f1,0, f1,256,
        xb, wp_f1, f1, zbuf, NULL,NULL,NULL,NULL, 2, 8);
    dw_k<256,true><<<16384, 256, 0, stream>>>(f1, wp_dwf, f2b_);
    // ffn2: BN=128, fp32 NCHW output via LDS transpose (two co-half passes)
    mconv_k<256,0,256,1,128,1,0><<<128*2*8, 256, 0, stream>>>(f2b_,256, NUL,0, wp_f2,0, outp,0,
        f2b_, wp_f2, outp, zbuf, NULL,NULL,NULL,NULL, 2, 8);
}